// Round 1
// baseline (295.207 us; speedup 1.0000x reference)
//
#include <hip/hip_runtime.h>
#include <stdint.h>

using u16    = unsigned short;
using short8 = __attribute__((ext_vector_type(8))) short;
using s16x4  = __attribute__((ext_vector_type(4))) short;
using f32x4  = __attribute__((ext_vector_type(4))) float;

constexpr float LOG2E = 1.44269504088896340736f;
constexpr float NEGINF_L2 = -1000000000.0f * 1.44269504088896340736f;

// ---- helpers ---------------------------------------------------------------

__device__ __forceinline__ u16 f2bf(float f) {
  uint32_t u = __builtin_bit_cast(uint32_t, f);
  return (u16)((u + 0x7fffu + ((u >> 16) & 1u)) >> 16);
}

__device__ __forceinline__ void gload16(const void* g, void* l) {
  __builtin_amdgcn_global_load_lds(
      (const __attribute__((address_space(1))) unsigned int*)g,
      (__attribute__((address_space(3))) unsigned int*)l, 16, 0, 0);
}

// 128-byte-row LDS tile, XOR-swizzled: phys = row*128 + (kbyte ^ ((row&7)<<4))
__device__ __forceinline__ short8 ldfrag(const u16* s, int row, int kbyte) {
  int phys = (row << 7) + (kbyte ^ ((row & 7) << 4));
  return *(const short8*)((const char*)s + phys);
}

// ---- prep: casts + weight transposes --------------------------------------
// xq/xr: bf16 [8192][512]; wqt/wkt/wvt: [c][d] = W[d][c]; wot: [d][c] = Wo[c][d]
__global__ __launch_bounds__(256) void prep_kernel(
    const float4* __restrict__ qin, const float4* __restrict__ rin,
    const float* __restrict__ wq, const float* __restrict__ wk,
    const float* __restrict__ wv, const float* __restrict__ wo,
    u16* __restrict__ xq, u16* __restrict__ xr,
    u16* __restrict__ wqt, u16* __restrict__ wkt,
    u16* __restrict__ wvt, u16* __restrict__ wot) {
  const int gid = blockIdx.x * blockDim.x + threadIdx.x;
  const int stride = gridDim.x * blockDim.x;
  for (int i = gid; i < (2 * 4096 * 512) / 4; i += stride) {
    float4 a = qin[i], b = rin[i];
    s16x4 va = {(short)f2bf(a.x), (short)f2bf(a.y), (short)f2bf(a.z), (short)f2bf(a.w)};
    s16x4 vb = {(short)f2bf(b.x), (short)f2bf(b.y), (short)f2bf(b.z), (short)f2bf(b.w)};
    *(s16x4*)(xq + i * 4) = va;
    *(s16x4*)(xr + i * 4) = vb;
  }
  for (int i = gid; i < 512 * 512; i += stride) {
    int orow = i >> 9, ocol = i & 511;
    int si = ocol * 512 + orow;  // transpose source
    wqt[i] = f2bf(wq[si]);
    wkt[i] = f2bf(wk[si]);
    wvt[i] = f2bf(wv[si]);
    wot[i] = f2bf(wo[si]);
  }
}

// ---- shared 128x128 tile GEMM core (C = A * Bt^T), K multiple of 64 --------
__device__ __forceinline__ void gemm_core(const u16* __restrict__ A, const u16* __restrict__ Bt,
                                          int K, u16* As, u16* Bs, int tm0, int tn0,
                                          f32x4 acc[4][4]) {
  const int tid = threadIdx.x;
  const int wv = tid >> 6, ln = tid & 63;
  const int lr = ln & 15, hi = ln >> 4;
  const int wr = wv >> 1, wc = wv & 1;
  const size_t rowbytes = (size_t)K * 2;
  for (int k0 = 0; k0 < K; k0 += 64) {
    __syncthreads();
    const char* Ab = (const char*)A + (size_t)tm0 * rowbytes + (size_t)k0 * 2;
    const char* Bb = (const char*)Bt + (size_t)tn0 * rowbytes + (size_t)k0 * 2;
#pragma unroll
    for (int c = 0; c < 4; ++c) {
      int lin = wv * 4096 + c * 1024 + ln * 16;
      int row = lin >> 7;
      int cb = (lin & 127) ^ ((row & 7) << 4);  // pre-swizzled global source
      gload16(Ab + (size_t)row * rowbytes + cb, (char*)As + wv * 4096 + c * 1024);
      gload16(Bb + (size_t)row * rowbytes + cb, (char*)Bs + wv * 4096 + c * 1024);
    }
    __syncthreads();
#pragma unroll
    for (int ks = 0; ks < 2; ++ks) {
      short8 af[4], bf[4];
#pragma unroll
      for (int m = 0; m < 4; ++m) af[m] = ldfrag(As, wr * 64 + m * 16 + lr, ks * 64 + hi * 16);
#pragma unroll
      for (int n = 0; n < 4; ++n) bf[n] = ldfrag(Bs, wc * 64 + n * 16 + lr, ks * 64 + hi * 16);
#pragma unroll
      for (int m = 0; m < 4; ++m)
#pragma unroll
        for (int n = 0; n < 4; ++n)
          acc[m][n] = __builtin_amdgcn_mfma_f32_16x16x32_bf16(af[m], bf[n], acc[m][n], 0, 0, 0);
    }
  }
}

// ---- QKV projection: z=0 -> q (scaled, [head][t][s]); z=1 -> k; z=2 -> v^T -
__global__ __launch_bounds__(256) void qkv_gemm(
    const u16* __restrict__ xq, const u16* __restrict__ xr,
    const u16* __restrict__ wqt, const u16* __restrict__ wkt, const u16* __restrict__ wvt,
    u16* __restrict__ qo, u16* __restrict__ ko, u16* __restrict__ vto) {
  __shared__ u16 As[128 * 64];
  __shared__ u16 Bs[128 * 64];
  const int z = blockIdx.z;
  const u16* A  = (z == 0) ? xq : xr;
  const u16* Bt = (z == 0) ? wqt : (z == 1) ? wkt : wvt;
  const int tm0 = blockIdx.x * 128, tn0 = blockIdx.y * 128;
  f32x4 acc[4][4];
#pragma unroll
  for (int m = 0; m < 4; ++m)
#pragma unroll
    for (int n = 0; n < 4; ++n) { f32x4 zz = {0.f, 0.f, 0.f, 0.f}; acc[m][n] = zz; }
  gemm_core(A, Bt, 512, As, Bs, tm0, tn0, acc);

  const int tid = threadIdx.x, wv = tid >> 6, ln = tid & 63, lr = ln & 15, hi = ln >> 4;
  const int wr = wv >> 1, wc = wv & 1;
  const float scale = (z == 0) ? 0.125f * LOG2E : 1.0f;  // fold log2e for exp2 softmax
#pragma unroll
  for (int m = 0; m < 4; ++m) {
#pragma unroll
    for (int n = 0; n < 4; ++n) {
#pragma unroll
      for (int r = 0; r < 4; ++r) {
        int rg = tm0 + wr * 64 + m * 16 + hi * 4 + r;  // global row in [0,8192)
        int cg = tn0 + wc * 64 + n * 16 + lr;          // global col in [0,512)
        int nb = rg >> 12, t = rg & 4095;
        int h = cg >> 6, s = cg & 63;
        int head = nb * 8 + h;
        u16 b = f2bf(acc[m][n][r] * scale);
        if (z == 0)      qo[((size_t)head * 4096 + t) * 64 + s] = b;
        else if (z == 1) ko[((size_t)head * 4096 + t) * 64 + s] = b;
        else             vto[((size_t)head * 64 + s) * 4096 + t] = b;
      }
    }
  }
}

// ---- flash attention: one (head, 64-row q-tile) per block ------------------
__global__ __launch_bounds__(256) void attn_kernel(
    const u16* __restrict__ q, const u16* __restrict__ k, const u16* __restrict__ vt,
    const float* __restrict__ mask, u16* __restrict__ ctx) {
  __shared__ u16 Ks[64 * 64];  // [key][s], swizzled
  __shared__ u16 Vs[64 * 64];  // [s][key], swizzled
  __shared__ u16 Ps[64 * 64];  // [q][key], swizzled, wave-private 16-row strips
  const int head = blockIdx.y;           // n*8 + h
  const int n = head >> 3, h = head & 7;
  const int qt0 = blockIdx.x << 6;
  const int tid = threadIdx.x, wv = tid >> 6, ln = tid & 63, lr = ln & 15, hi = ln >> 4;

  const u16* qh = q + (size_t)head * 4096 * 64;
  const char* kh = (const char*)(k + (size_t)head * 4096 * 64);
  const char* vth = (const char*)(vt + (size_t)head * 64 * 4096);
  const float* mrow = mask + (size_t)n * 4096;

  // q fragments for this wave's 16 rows (A-operand: row=lr, k = ks*32 + hi*8 + j)
  short8 qf0, qf1;
  {
    const u16* qp = qh + (size_t)(qt0 + wv * 16 + lr) * 64;
    qf0 = *(const short8*)(qp + hi * 8);
    qf1 = *(const short8*)(qp + 32 + hi * 8);
  }

  f32x4 cacc[4];
#pragma unroll
  for (int sb = 0; sb < 4; ++sb) { f32x4 zz = {0.f, 0.f, 0.f, 0.f}; cacc[sb] = zz; }
  float mrun[4] = {-__builtin_inff(), -__builtin_inff(), -__builtin_inff(), -__builtin_inff()};
  float lrun[4] = {0.f, 0.f, 0.f, 0.f};

  for (int kt = 0; kt < 4096; kt += 64) {
    __syncthreads();  // protect Ks/Vs against previous iteration's readers
    {
      const char* kb = kh + (size_t)kt * 128;
#pragma unroll
      for (int c = 0; c < 2; ++c) {
        int lin = wv * 2048 + c * 1024 + ln * 16;
        int row = lin >> 7;
        int cb = (lin & 127) ^ ((row & 7) << 4);
        gload16(kb + (size_t)row * 128 + cb, (char*)Ks + wv * 2048 + c * 1024);
        gload16(vth + (size_t)row * 8192 + (size_t)kt * 2 + cb, (char*)Vs + wv * 2048 + c * 1024);
      }
    }
    __syncthreads();

    // QK^T: 4 key-groups of 16; scores already in log2 domain (q pre-scaled)
    f32x4 sv[4];
#pragma unroll
    for (int kg = 0; kg < 4; ++kg) {
      short8 kf0 = ldfrag(Ks, kg * 16 + lr, hi * 16);
      short8 kf1 = ldfrag(Ks, kg * 16 + lr, 64 + hi * 16);
      f32x4 c = {0.f, 0.f, 0.f, 0.f};
      c = __builtin_amdgcn_mfma_f32_16x16x32_bf16(qf0, kf0, c, 0, 0, 0);
      c = __builtin_amdgcn_mfma_f32_16x16x32_bf16(qf1, kf1, c, 0, 0, 0);
      float mk = mrow[kt + kg * 16 + lr] * NEGINF_L2;  // column mask term
      c[0] += mk; c[1] += mk; c[2] += mk; c[3] += mk;
      sv[kg] = c;
    }

    // wave-parallel online softmax (rows live at lanes' 4*hi+r)
    float rm[4];
#pragma unroll
    for (int r = 0; r < 4; ++r)
      rm[r] = fmaxf(fmaxf(sv[0][r], sv[1][r]), fmaxf(sv[2][r], sv[3][r]));
#pragma unroll
    for (int off = 1; off < 16; off <<= 1) {
#pragma unroll
      for (int r = 0; r < 4; ++r) rm[r] = fmaxf(rm[r], __shfl_xor(rm[r], off));
    }
    float sc[4];
#pragma unroll
    for (int r = 0; r < 4; ++r) {
      float mn = fmaxf(mrun[r], rm[r]);
      sc[r] = exp2f(mrun[r] - mn);  // first iter: exp2(-inf)=0
      mrun[r] = mn;
    }
    float p[4][4];
#pragma unroll
    for (int kg = 0; kg < 4; ++kg)
#pragma unroll
      for (int r = 0; r < 4; ++r) p[kg][r] = exp2f(sv[kg][r] - mrun[r]);
    float ps[4];
#pragma unroll
    for (int r = 0; r < 4; ++r) ps[r] = (p[0][r] + p[1][r]) + (p[2][r] + p[3][r]);
#pragma unroll
    for (int off = 1; off < 16; off <<= 1) {
#pragma unroll
      for (int r = 0; r < 4; ++r) ps[r] += __shfl_xor(ps[r], off);
    }
#pragma unroll
    for (int r = 0; r < 4; ++r) lrun[r] = lrun[r] * sc[r] + ps[r];
    {
      f32x4 scv = {sc[0], sc[1], sc[2], sc[3]};
#pragma unroll
      for (int sb = 0; sb < 4; ++sb) cacc[sb] *= scv;
    }

    // P -> wave-private LDS strip (bf16, swizzled); rows wv*16 .. wv*16+15
#pragma unroll
    for (int kg = 0; kg < 4; ++kg)
#pragma unroll
      for (int r = 0; r < 4; ++r) {
        int row = wv * 16 + hi * 4 + r;
        int kbyte = (kg * 16 + lr) * 2;
        int phys = (row << 7) + (kbyte ^ ((row & 7) << 4));
        *(u16*)((char*)Ps + phys) = f2bf(p[kg][r]);
      }

    // PV: ctx[16q x 64s] += P[16x64] * V[64x64]  (V from Vs = V^T rows)
    short8 pf0 = ldfrag(Ps, wv * 16 + lr, hi * 16);
    short8 pf1 = ldfrag(Ps, wv * 16 + lr, 64 + hi * 16);
#pragma unroll
    for (int sb = 0; sb < 4; ++sb) {
      short8 v0 = ldfrag(Vs, sb * 16 + lr, hi * 16);
      short8 v1 = ldfrag(Vs, sb * 16 + lr, 64 + hi * 16);
      cacc[sb] = __builtin_amdgcn_mfma_f32_16x16x32_bf16(pf0, v0, cacc[sb], 0, 0, 0);
      cacc[sb] = __builtin_amdgcn_mfma_f32_16x16x32_bf16(pf1, v1, cacc[sb], 0, 0, 0);
    }
  }

  // normalize and store ctx as bf16 [n][t][h*64+s]
  float inv[4];
#pragma unroll
  for (int r = 0; r < 4; ++r) inv[r] = 1.0f / lrun[r];
#pragma unroll
  for (int sb = 0; sb < 4; ++sb)
#pragma unroll
    for (int r = 0; r < 4; ++r) {
      size_t t = (size_t)(n * 4096 + qt0 + wv * 16 + hi * 4 + r);
      ctx[t * 512 + h * 64 + sb * 16 + lr] = f2bf(cacc[sb][r] * inv[r]);
    }
}

// ---- output projection: out[8192][512] fp32 = ctx * WoT^T ------------------
__global__ __launch_bounds__(256) void out_gemm(
    const u16* __restrict__ ctx, const u16* __restrict__ wot, float* __restrict__ out) {
  __shared__ u16 As[128 * 64];
  __shared__ u16 Bs[128 * 64];
  const int tm0 = blockIdx.x * 128, tn0 = blockIdx.y * 128;
  f32x4 acc[4][4];
#pragma unroll
  for (int m = 0; m < 4; ++m)
#pragma unroll
    for (int n = 0; n < 4; ++n) { f32x4 zz = {0.f, 0.f, 0.f, 0.f}; acc[m][n] = zz; }
  gemm_core(ctx, wot, 512, As, Bs, tm0, tn0, acc);

  const int tid = threadIdx.x, wv = tid >> 6, ln = tid & 63, lr = ln & 15, hi = ln >> 4;
  const int wr = wv >> 1, wc = wv & 1;
#pragma unroll
  for (int m = 0; m < 4; ++m)
#pragma unroll
    for (int n = 0; n < 4; ++n)
#pragma unroll
      for (int r = 0; r < 4; ++r) {
        int rg = tm0 + wr * 64 + m * 16 + hi * 4 + r;
        int cg = tn0 + wc * 64 + n * 16 + lr;
        out[(size_t)rg * 512 + cg] = acc[m][n][r];
      }
}

// ---- launch ----------------------------------------------------------------
extern "C" void kernel_launch(void* const* d_in, const int* in_sizes, int n_in,
                              void* d_out, int out_size, void* d_ws, size_t ws_size,
                              hipStream_t stream) {
  (void)in_sizes; (void)n_in; (void)out_size; (void)ws_size;
  const float* qin  = (const float*)d_in[0];
  const float* rin  = (const float*)d_in[1];
  const float* mask = (const float*)d_in[2];
  const float* wq   = (const float*)d_in[3];
  const float* wk   = (const float*)d_in[4];
  const float* wv   = (const float*)d_in[5];
  const float* wo   = (const float*)d_in[6];

  char* ws = (char*)d_ws;
  u16* xq  = (u16*)(ws + 0);         // [8192][512] bf16
  u16* xr  = (u16*)(ws + 8388608);   // [8192][512]
  u16* wqt = (u16*)(ws + 16777216);  // [512][512] transposed
  u16* wkt = (u16*)(ws + 17301504);
  u16* wvt = (u16*)(ws + 17825792);
  u16* wot = (u16*)(ws + 18350080);
  u16* qo  = (u16*)(ws + 18874368);  // [16][4096][64]
  u16* ko  = (u16*)(ws + 27262976);  // [16][4096][64]
  u16* vto = (u16*)(ws + 35651584);  // [16][64][4096]
  u16* ctx = (u16*)(ws + 44040192);  // [8192][512]

  prep_kernel<<<2048, 256, 0, stream>>>((const float4*)qin, (const float4*)rin,
                                        wq, wk, wv, wo, xq, xr, wqt, wkt, wvt, wot);
  qkv_gemm<<<dim3(64, 4, 3), 256, 0, stream>>>(xq, xr, wqt, wkt, wvt, qo, ko, vto);
  attn_kernel<<<dim3(64, 16), 256, 0, stream>>>(qo, ko, vto, mask, ctx);
  out_gemm<<<dim3(64, 4), 256, 0, stream>>>(ctx, wot, (float*)d_out);
}

// Round 2
// 167.898 us; speedup vs baseline: 1.7583x; 1.7583x over previous
//
#include <hip/hip_runtime.h>
#include <stdint.h>

using u16    = unsigned short;
using u32    = unsigned int;
using short8 = __attribute__((ext_vector_type(8))) short;
using s16x4  = __attribute__((ext_vector_type(4))) short;
using f32x4  = __attribute__((ext_vector_type(4))) float;
using f32x16 = __attribute__((ext_vector_type(16))) float;
using i32x4  = __attribute__((ext_vector_type(4))) int;

constexpr float LOG2E = 1.44269504088896340736f;

// ---- helpers ---------------------------------------------------------------

__device__ __forceinline__ u16 f2bf(float f) {
  uint32_t u = __builtin_bit_cast(uint32_t, f);
  return (u16)((u + 0x7fffu + ((u >> 16) & 1u)) >> 16);
}

__device__ __forceinline__ void gload16(const void* g, void* l) {
  __builtin_amdgcn_global_load_lds(
      (const __attribute__((address_space(1))) unsigned int*)g,
      (__attribute__((address_space(3))) unsigned int*)l, 16, 0, 0);
}

__device__ __forceinline__ u32 cvtpk_bf16(float lo, float hi) {
  u32 r;
  asm("v_cvt_pk_bf16_f32 %0, %1, %2" : "=v"(r) : "v"(lo), "v"(hi));
  return r;
}

__device__ __forceinline__ f32x16 zero16() {
  f32x16 z;
#pragma unroll
  for (int i = 0; i < 16; ++i) z[i] = 0.f;
  return z;
}

// 128-byte-row LDS tile, XOR-swizzled (GEMM staging path)
__device__ __forceinline__ short8 ldfrag(const u16* s, int row, int kbyte) {
  int phys = (row << 7) + (kbyte ^ ((row & 7) << 4));
  return *(const short8*)((const char*)s + phys);
}

// ---- prep: casts + weight transposes + K-aug mask column -------------------
__global__ __launch_bounds__(256) void prep_kernel(
    const float4* __restrict__ qin, const float4* __restrict__ rin,
    const float* __restrict__ mask,
    const float* __restrict__ wq, const float* __restrict__ wk,
    const float* __restrict__ wv, const float* __restrict__ wo,
    u16* __restrict__ xq, u16* __restrict__ xr,
    u16* __restrict__ wqt, u16* __restrict__ wkt,
    u16* __restrict__ wvt, u16* __restrict__ wot,
    u16* __restrict__ kaug) {
  const int gid = blockIdx.x * blockDim.x + threadIdx.x;
  const int stride = gridDim.x * blockDim.x;
  for (int i = gid; i < (2 * 4096 * 512) / 4; i += stride) {
    float4 a = qin[i], b = rin[i];
    s16x4 va = {(short)f2bf(a.x), (short)f2bf(a.y), (short)f2bf(a.z), (short)f2bf(a.w)};
    s16x4 vb = {(short)f2bf(b.x), (short)f2bf(b.y), (short)f2bf(b.z), (short)f2bf(b.w)};
    *(s16x4*)(xq + i * 4) = va;
    *(s16x4*)(xr + i * 4) = vb;
  }
  for (int i = gid; i < 512 * 512; i += stride) {
    int orow = i >> 9, ocol = i & 511;
    int si = ocol * 512 + orow;  // transpose source
    wqt[i] = f2bf(wq[si]);
    wkt[i] = f2bf(wk[si]);
    wvt[i] = f2bf(wv[si]);
    wot[i] = f2bf(wo[si]);
  }
  // augmented K columns 64..79: [mask*NEG_INF*log2e, 0 x15]
  for (int i = gid; i < 16 * 4096; i += stride) {
    int head = i >> 12, t = i & 4095;
    int nn = head >> 3;
    float mt = mask[nn * 4096 + t] * (-1.0e9f * LOG2E);
    u16* kp = kaug + ((size_t)head * 4096 + t) * 80 + 64;
    kp[0] = f2bf(mt);
#pragma unroll
    for (int c = 1; c < 16; ++c) kp[c] = 0;
  }
}

// ---- shared 128x128 tile GEMM core (C = A * Bt^T), K multiple of 64 --------
__device__ __forceinline__ void gemm_core(const u16* __restrict__ A, const u16* __restrict__ Bt,
                                          int K, u16* As, u16* Bs, int tm0, int tn0,
                                          f32x4 acc[4][4]) {
  const int tid = threadIdx.x;
  const int wv = tid >> 6, ln = tid & 63;
  const int lr = ln & 15, hi = ln >> 4;
  const int wr = wv >> 1, wc = wv & 1;
  const size_t rowbytes = (size_t)K * 2;
  for (int k0 = 0; k0 < K; k0 += 64) {
    __syncthreads();
    const char* Ab = (const char*)A + (size_t)tm0 * rowbytes + (size_t)k0 * 2;
    const char* Bb = (const char*)Bt + (size_t)tn0 * rowbytes + (size_t)k0 * 2;
#pragma unroll
    for (int c = 0; c < 4; ++c) {
      int lin = wv * 4096 + c * 1024 + ln * 16;
      int row = lin >> 7;
      int cb = (lin & 127) ^ ((row & 7) << 4);  // pre-swizzled global source
      gload16(Ab + (size_t)row * rowbytes + cb, (char*)As + wv * 4096 + c * 1024);
      gload16(Bb + (size_t)row * rowbytes + cb, (char*)Bs + wv * 4096 + c * 1024);
    }
    __syncthreads();
#pragma unroll
    for (int ks = 0; ks < 2; ++ks) {
      short8 af[4], bf[4];
#pragma unroll
      for (int m = 0; m < 4; ++m) af[m] = ldfrag(As, wr * 64 + m * 16 + lr, ks * 64 + hi * 16);
#pragma unroll
      for (int n = 0; n < 4; ++n) bf[n] = ldfrag(Bs, wc * 64 + n * 16 + lr, ks * 64 + hi * 16);
#pragma unroll
      for (int m = 0; m < 4; ++m)
#pragma unroll
        for (int n = 0; n < 4; ++n)
          acc[m][n] = __builtin_amdgcn_mfma_f32_16x16x32_bf16(af[m], bf[n], acc[m][n], 0, 0, 0);
    }
  }
}

// ---- QKV projection: z=0 -> q (scaled); z=1 -> k_aug (stride 80); z=2 -> v^T
__global__ __launch_bounds__(256) void qkv_gemm(
    const u16* __restrict__ xq, const u16* __restrict__ xr,
    const u16* __restrict__ wqt, const u16* __restrict__ wkt, const u16* __restrict__ wvt,
    u16* __restrict__ qo, u16* __restrict__ ko, u16* __restrict__ vto) {
  __shared__ u16 As[128 * 64];
  __shared__ u16 Bs[128 * 64];
  const int z = blockIdx.z;
  const u16* A  = (z == 0) ? xq : xr;
  const u16* Bt = (z == 0) ? wqt : (z == 1) ? wkt : wvt;
  const int tm0 = blockIdx.x * 128, tn0 = blockIdx.y * 128;
  f32x4 acc[4][4];
#pragma unroll
  for (int m = 0; m < 4; ++m)
#pragma unroll
    for (int n = 0; n < 4; ++n) { f32x4 zz = {0.f, 0.f, 0.f, 0.f}; acc[m][n] = zz; }
  gemm_core(A, Bt, 512, As, Bs, tm0, tn0, acc);

  const int tid = threadIdx.x, wv = tid >> 6, ln = tid & 63, lr = ln & 15, hi = ln >> 4;
  const int wr = wv >> 1, wc = wv & 1;
  const float scale = (z == 0) ? 0.125f * LOG2E : 1.0f;  // fold log2e for exp2 softmax
#pragma unroll
  for (int m = 0; m < 4; ++m) {
#pragma unroll
    for (int n = 0; n < 4; ++n) {
#pragma unroll
      for (int r = 0; r < 4; ++r) {
        int rg = tm0 + wr * 64 + m * 16 + hi * 4 + r;  // global row in [0,8192)
        int cg = tn0 + wc * 64 + n * 16 + lr;          // global col in [0,512)
        int nb = rg >> 12, t = rg & 4095;
        int h = cg >> 6, s = cg & 63;
        int head = nb * 8 + h;
        u16 b = f2bf(acc[m][n][r] * scale);
        if (z == 0)      qo[((size_t)head * 4096 + t) * 64 + s] = b;
        else if (z == 1) ko[((size_t)head * 4096 + t) * 80 + s] = b;
        else             vto[((size_t)head * 64 + s) * 4096 + t] = b;
      }
    }
  }
}

// ---- flash attention v2: swapped 32x32 MFMA, in-register softmax -----------
// grid (16 heads, 16 qblocks), 512 threads (8 waves x QBLK=32)
__global__ __launch_bounds__(512, 2) void attn2_kernel(
    const u16* __restrict__ q, const u16* __restrict__ kaug, const u16* __restrict__ vt,
    u16* __restrict__ ctx) {
  // frag-major LDS: K slots 0..9 ((t<2)*5+ks), V slots 10..17 (10+ks*2+st), 1KB each
  __shared__ __align__(16) char lds[2][18432];
  const int head = blockIdx.x, qb = blockIdx.y;
  const int n = head >> 3, h = head & 7;
  const int tid = threadIdx.x, wv = tid >> 6, ln = tid & 63;
  const int lq = ln & 31, hi = ln >> 5, hi4 = hi * 4;
  const int q0 = qb * 256 + wv * 32;

  const char* kh = (const char*)(kaug + (size_t)head * 4096 * 80);
  const char* vh = (const char*)(vt + (size_t)head * 64 * 4096);

  // Q fragments (B-operand): lane -> Q[q0+lq][16ks+8hi+j]; qf[4] = aug unit col
  short8 qf[5];
  {
    const char* qp = (const char*)(q + (size_t)head * 4096 * 64) + (size_t)(q0 + lq) * 128 + hi * 16;
#pragma unroll
    for (int ks = 0; ks < 4; ++ks) qf[ks] = *(const short8*)(qp + ks * 32);
    short8 z = {0, 0, 0, 0, 0, 0, 0, 0};
    if (hi == 0) z[0] = (short)0x3F80;  // bf16 1.0 at s=64
    qf[4] = z;
  }

  f32x16 cacc0 = zero16(), cacc1 = zero16();
  float mrun = -3.0e38f, lrun = 0.f;

  auto stage = [&](int buf, int kt0) {
    char* base = lds[buf];
    for (int s = wv; s < 18; s += 8) {
      const char* src;
      if (s < 10) {
        int t = (s >= 5) ? 1 : 0, ks = s - t * 5;
        src = kh + (size_t)(kt0 + t * 32 + lq) * 160 + ks * 32 + hi * 16;
      } else {
        int j = s - 10, ks = j >> 1, st = j & 1;
        src = vh + (size_t)(st * 32 + lq) * 8192 + (size_t)(kt0 + ks * 16 + hi * 8) * 2;
      }
      gload16(src, base + (s << 10));  // HW: lds dst = base + lane*16
    }
  };

  stage(0, 0);
  __syncthreads();

  for (int it = 0; it < 64; ++it) {
    const int cur = it & 1;
    if (it < 63) stage(cur ^ 1, (it + 1) * 64);
    const char* base = lds[cur];

    // QK^T (swapped: A=K rows=key, B=Q cols=q) -> S[reg=key][lane=q]
    f32x16 S0 = zero16(), S1 = zero16();
#pragma unroll
    for (int ks = 0; ks < 5; ++ks) {
      short8 k0 = *(const short8*)(base + (ks << 10) + (ln << 4));
      short8 k1 = *(const short8*)(base + ((5 + ks) << 10) + (ln << 4));
      S0 = __builtin_amdgcn_mfma_f32_32x32x16_bf16(k0, qf[ks], S0, 0, 0, 0);
      S1 = __builtin_amdgcn_mfma_f32_32x32x16_bf16(k1, qf[ks], S1, 0, 0, 0);
    }

    // row max: in-register + one cross-half exchange
    float mx = S0[0];
#pragma unroll
    for (int r = 1; r < 16; ++r) mx = fmaxf(mx, S0[r]);
#pragma unroll
    for (int r = 0; r < 16; ++r) mx = fmaxf(mx, S1[r]);
    mx = fmaxf(mx, __shfl_xor(mx, 32));

    // defer-max (T13): only rescale when tile max grew past threshold
    if (!__all(mx <= mrun + 8.0f)) {
      float mn = fmaxf(mrun, mx);
      float sc = __builtin_amdgcn_exp2f(mrun - mn);
      mrun = mn;
      lrun *= sc;
      int sci = __builtin_bit_cast(int, sc);
#pragma unroll
      for (int r = 0; r < 16; ++r) {
        int cr = (r & 3) + ((r >> 2) << 3) + hi4;  // q owning this acc reg
        float s2 = __builtin_bit_cast(float, __builtin_amdgcn_ds_bpermute(cr << 2, sci));
        cacc0[r] *= s2;
        cacc1[r] *= s2;
      }
    }

    float psum = 0.f;
    float p0[16], p1[16];
#pragma unroll
    for (int r = 0; r < 16; ++r) { p0[r] = __builtin_amdgcn_exp2f(S0[r] - mrun); psum += p0[r]; }
#pragma unroll
    for (int r = 0; r < 16; ++r) { p1[r] = __builtin_amdgcn_exp2f(S1[r] - mrun); psum += p1[r]; }
    psum += __shfl_xor(psum, 32);
    lrun += psum;

    // build PV A-frags: pa[key-slot of 16], key order via cross-half exchange
    short8 pa0, pa1, pa2, pa3;
#define SHF32(x) ((u32)__shfl_xor((int)(x), 32))
#define MKFRAGS(P, FA, FB)                                                          \
    {                                                                               \
      u32 A01 = cvtpk_bf16(P[0], P[1]), B23 = cvtpk_bf16(P[2], P[3]);               \
      u32 C45 = cvtpk_bf16(P[4], P[5]), D67 = cvtpk_bf16(P[6], P[7]);               \
      u32 E89 = cvtpk_bf16(P[8], P[9]), F01 = cvtpk_bf16(P[10], P[11]);             \
      u32 G23 = cvtpk_bf16(P[12], P[13]), H45 = cvtpk_bf16(P[14], P[15]);           \
      u32 A01x = SHF32(A01), B23x = SHF32(B23), C45x = SHF32(C45), D67x = SHF32(D67);\
      u32 E89x = SHF32(E89), F01x = SHF32(F01), G23x = SHF32(G23), H45x = SHF32(H45);\
      i32x4 fa = {(int)(hi ? C45x : A01), (int)(hi ? D67x : B23),                   \
                  (int)(hi ? C45 : A01x), (int)(hi ? D67 : B23x)};                  \
      i32x4 fb = {(int)(hi ? G23x : E89), (int)(hi ? H45x : F01),                   \
                  (int)(hi ? G23 : E89x), (int)(hi ? H45 : F01x)};                  \
      FA = __builtin_bit_cast(short8, fa);                                          \
      FB = __builtin_bit_cast(short8, fb);                                          \
    }
    MKFRAGS(p0, pa0, pa1);
    MKFRAGS(p1, pa2, pa3);
#undef MKFRAGS
#undef SHF32

    // PV: cacc[st] += P[q][key] * V[key][s]
#pragma unroll
    for (int ks = 0; ks < 4; ++ks) {
      short8 pa = (ks == 0) ? pa0 : (ks == 1) ? pa1 : (ks == 2) ? pa2 : pa3;
      short8 v0 = *(const short8*)(base + ((10 + ks * 2 + 0) << 10) + (ln << 4));
      short8 v1 = *(const short8*)(base + ((10 + ks * 2 + 1) << 10) + (ln << 4));
      cacc0 = __builtin_amdgcn_mfma_f32_32x32x16_bf16(pa, v0, cacc0, 0, 0, 0);
      cacc1 = __builtin_amdgcn_mfma_f32_32x32x16_bf16(pa, v1, cacc1, 0, 0, 0);
    }

    __syncthreads();  // drains our stage loads (vmcnt) + publishes next buffer
  }

  // normalize + store ctx[n][t][h*64 + s] bf16
  float li = 1.0f / lrun;
  int lii = __builtin_bit_cast(int, li);
  u16* cp = ctx + (size_t)(n * 4096 + q0) * 512 + h * 64;
#pragma unroll
  for (int r = 0; r < 16; ++r) {
    int cr = (r & 3) + ((r >> 2) << 3) + hi4;
    float inv = __builtin_bit_cast(float, __builtin_amdgcn_ds_bpermute(cr << 2, lii));
    cp[(size_t)cr * 512 + lq] = f2bf(cacc0[r] * inv);
    cp[(size_t)cr * 512 + 32 + lq] = f2bf(cacc1[r] * inv);
  }
}

// ---- output projection: out[8192][512] fp32 = ctx * WoT^T ------------------
__global__ __launch_bounds__(256) void out_gemm(
    const u16* __restrict__ ctx, const u16* __restrict__ wot, float* __restrict__ out) {
  __shared__ u16 As[128 * 64];
  __shared__ u16 Bs[128 * 64];
  const int tm0 = blockIdx.x * 128, tn0 = blockIdx.y * 128;
  f32x4 acc[4][4];
#pragma unroll
  for (int m = 0; m < 4; ++m)
#pragma unroll
    for (int n = 0; n < 4; ++n) { f32x4 zz = {0.f, 0.f, 0.f, 0.f}; acc[m][n] = zz; }
  gemm_core(ctx, wot, 512, As, Bs, tm0, tn0, acc);

  const int tid = threadIdx.x, wv = tid >> 6, ln = tid & 63, lr = ln & 15, hi = ln >> 4;
  const int wr = wv >> 1, wc = wv & 1;
#pragma unroll
  for (int m = 0; m < 4; ++m)
#pragma unroll
    for (int n = 0; n < 4; ++n)
#pragma unroll
      for (int r = 0; r < 4; ++r) {
        int rg = tm0 + wr * 64 + m * 16 + hi * 4 + r;
        int cg = tn0 + wc * 64 + n * 16 + lr;
        out[(size_t)rg * 512 + cg] = acc[m][n][r];
      }
}

// ---- launch ----------------------------------------------------------------
extern "C" void kernel_launch(void* const* d_in, const int* in_sizes, int n_in,
                              void* d_out, int out_size, void* d_ws, size_t ws_size,
                              hipStream_t stream) {
  (void)in_sizes; (void)n_in; (void)out_size; (void)ws_size;
  const float* qin  = (const float*)d_in[0];
  const float* rin  = (const float*)d_in[1];
  const float* mask = (const float*)d_in[2];
  const float* wq   = (const float*)d_in[3];
  const float* wk   = (const float*)d_in[4];
  const float* wv   = (const float*)d_in[5];
  const float* wo   = (const float*)d_in[6];

  char* ws = (char*)d_ws;
  u16* xq   = (u16*)(ws + 0);         // [8192][512] bf16 (region reused by ctx)
  u16* ctx  = (u16*)(ws + 0);         // [8192][512] bf16 (written after xq dead)
  u16* xr   = (u16*)(ws + 8388608);   // [8192][512]
  u16* wqt  = (u16*)(ws + 16777216);  // [512][512] transposed
  u16* wkt  = (u16*)(ws + 17301504);
  u16* wvt  = (u16*)(ws + 17825792);
  u16* wot  = (u16*)(ws + 18350080);
  u16* qo   = (u16*)(ws + 18874368);  // [16][4096][64]
  u16* kaug = (u16*)(ws + 27262976);  // [16][4096][80] (cols 64.. = mask aug)
  u16* vto  = (u16*)(ws + 37748736);  // [16][64][4096]

  prep_kernel<<<2048, 256, 0, stream>>>((const float4*)qin, (const float4*)rin, mask,
                                        wq, wk, wv, wo, xq, xr, wqt, wkt, wvt, wot, kaug);
  qkv_gemm<<<dim3(64, 4, 3), 256, 0, stream>>>(xq, xr, wqt, wkt, wvt, qo, kaug, vto);
  attn2_kernel<<<dim3(16, 16), 512, 0, stream>>>(qo, kaug, vto, ctx);
  out_gemm<<<dim3(64, 4), 256, 0, stream>>>(ctx, wot, (float*)d_out);
}